// Round 5
// baseline (81.183 us; speedup 1.0000x reference)
//
#include <hip/hip_runtime.h>

#define HDIM 8
#define CHUNK 16   // steps per LDS chunk (T=512 -> 32 chunks)

// ---- fast device math (v_exp_f32 / v_rcp_f32) ----
__device__ __forceinline__ float ex2(float x) {
#if __has_builtin(__builtin_amdgcn_exp2f)
    return __builtin_amdgcn_exp2f(x);
#else
    return exp2f(x);
#endif
}
__device__ __forceinline__ float rcp(float x) {
#if __has_builtin(__builtin_amdgcn_rcpf)
    return __builtin_amdgcn_rcpf(x);
#else
    return 1.0f / x;
#endif
}

// v_mov_b32_dpp row_ror:N (N immediate). 0x120+N = ROW_ROR DPP ctrl.
#define DPP_ROR(v, N)                                                        \
    __int_as_float(__builtin_amdgcn_update_dpp(                              \
        0, __float_as_int(v), 0x120 + (N), 0xF, 0xF, true))

// LDS projection buffer layout: [buf][gru][s][el][j*4 .. j*4+3] (floats)
// float offset inside one (buf,gru) region: (s*8 + el)*32 + j*4

// ---- producer: compute prescaled input projections for one 16-step chunk ----
// lane (el, q): handles steps s = q and q+8 of the chunk; computes all 24 gate
// rows for that step and writes 8 float4 (pr,pz,pn,0) to LDS.
template <int IN, int STRIDE>
__device__ __forceinline__ void produce_chunk(
    const float* __restrict__ xb, int t0,
    const float (&uir)[8][4], const float (&uiz)[8][4], const float (&uin)[8][4],
    const float (&cr)[8], const float (&cz)[8], const float (&cn)[8],
    float* dst, int el, int q)
{
#pragma unroll
    for (int h = 0; h < 2; ++h) {
        const int s = q + 8 * h;
        const float* p = xb + (size_t)(t0 + s) * STRIDE;
        float x[IN];
        if constexpr (IN == 4) {
            float4 v = *reinterpret_cast<const float4*>(p);
            x[0] = v.x; x[1] = v.y; x[2] = v.z; x[3] = v.w;
        } else {
            float2 v = *reinterpret_cast<const float2*>(p);
            x[0] = v.x; x[1] = v.y;
        }
#pragma unroll
        for (int jj = 0; jj < 8; ++jj) {
            float a = cr[jj], b = cz[jj], c = cn[jj];
#pragma unroll
            for (int i = 0; i < IN; ++i) {
                a = fmaf(uir[jj][i], x[i], a);
                b = fmaf(uiz[jj][i], x[i], b);
                c = fmaf(uin[jj][i], x[i], c);
            }
            *reinterpret_cast<float4*>(dst + (size_t)(s * 8 + el) * 32 + jj * 4)
                = make_float4(a, b, c, 0.0f);
        }
    }
}

// ---- consumer: run 16 recurrence steps from LDS projections ----
__device__ __forceinline__ float consume_chunk(
    float hj, const float* __restrict__ src, int el, int j,
    const float (&wr)[8], const float (&wz)[8], const float (&wn)[8], float bhn)
{
    float4 pf[3];
    pf[0] = *reinterpret_cast<const float4*>(src + (size_t)(0 * 8 + el) * 32 + j * 4);
    pf[1] = *reinterpret_cast<const float4*>(src + (size_t)(1 * 8 + el) * 32 + j * 4);
#pragma unroll
    for (int s = 0; s < CHUNK; ++s) {
        if (s + 2 < CHUNK)
            pf[(s + 2) % 3] = *reinterpret_cast<const float4*>(
                src + (size_t)((s + 2) * 8 + el) * 32 + j * 4);
        const float4 P = pf[s % 3];   // (pr, pz, pn, 0) prescaled

        // h all-gather: 7 DPP row-rotations (VALU only)
        const float hx0 = hj;
        const float hx1 = DPP_ROR(hj,  2);
        const float hx2 = DPP_ROR(hj,  4);
        const float hx3 = DPP_ROR(hj,  6);
        const float hx4 = DPP_ROR(hj,  8);
        const float hx5 = DPP_ROR(hj, 10);
        const float hx6 = DPP_ROR(hj, 12);
        const float hx7 = DPP_ROR(hj, 14);

        // balanced trees, proj/bias folded into first pair
        float r01 = fmaf(wr[1], hx1, fmaf(wr[0], hx0, P.x));
        float r23 = fmaf(wr[3], hx3, wr[2] * hx2);
        float r45 = fmaf(wr[5], hx5, wr[4] * hx4);
        float r67 = fmaf(wr[7], hx7, wr[6] * hx6);
        float z01 = fmaf(wz[1], hx1, fmaf(wz[0], hx0, P.y));
        float z23 = fmaf(wz[3], hx3, wz[2] * hx2);
        float z45 = fmaf(wz[5], hx5, wz[4] * hx4);
        float z67 = fmaf(wz[7], hx7, wz[6] * hx6);
        float n01 = fmaf(wn[1], hx1, fmaf(wn[0], hx0, bhn));
        float n23 = fmaf(wn[3], hx3, wn[2] * hx2);
        float n45 = fmaf(wn[5], hx5, wn[4] * hx4);
        float n67 = fmaf(wn[7], hx7, wn[6] * hx6);
        float sr = (r01 + r23) + (r45 + r67);
        float sz = (z01 + z23) + (z45 + z67);
        float sn = (n01 + n23) + (n45 + n67);

        float r = rcp(1.0f + ex2(sr));              // sigmoid (prescaled arg)
        float z = rcp(1.0f + ex2(sz));
        float u = fmaf(r, sn, P.z);                 // 2log2e*(an + r*hn)
        float n = fmaf(-2.0f, rcp(1.0f + ex2(u)), 1.0f);  // tanh
        hj = fmaf(z, hj - n, n);                    // (1-z)*n + z*h
    }
    return hj;
}

// block = 256 threads = 4 waves.
//   wave 0: consumer, bbox GRU   wave 1: consumer, flow GRU
//   wave 2: producer, bbox proj  wave 3: producer, flow proj
// Producers stage prescaled projections into double-buffered LDS chunks;
// consumers run the pure-VALU recurrence (DPP h-gather, no global access).
__global__ __launch_bounds__(256, 1)
void gru_fused_kernel(const float* __restrict__ bbox, const float* __restrict__ flow,
                      const float* __restrict__ Wih_b, const float* __restrict__ Whh_b,
                      const float* __restrict__ bih_b, const float* __restrict__ bhh_b,
                      const float* __restrict__ Wih_f, const float* __restrict__ Whh_f,
                      const float* __restrict__ bih_f, const float* __restrict__ bhh_f,
                      float* __restrict__ out, int T)
{
    const float NL2E = -1.4426950408889634f;  // -log2(e)
    const float L2E2 =  2.8853900817779268f;  //  2*log2(e)

    __shared__ float projLDS[2][2][CHUNK][8][32];   // 64 KiB
    __shared__ float sh[2][8][HDIM];

    const int tid  = threadIdx.x;
    const int wave = tid >> 6;
    const int lane = tid & 63;
    const int gru  = wave & 1;            // 0 = bbox, 1 = flow
    const bool is_cons = (wave < 2);
    const int NC = T / CHUNK;             // T=512 -> 32

    // ---- consumer state ----
    const int eloc = ((lane >> 4) << 1) | (lane & 1);   // element 0..7
    const int j    = (lane & 15) >> 1;                  // hidden unit 0..7
    float wr[8], wz[8], wn[8];
    float bhn = 0.0f;

    // ---- producer state ----
    float uir[8][4], uiz[8][4], uin[8][4], cr[8], cz[8], cn[8];
    const float* pxb = nullptr;
    const int pel = lane >> 3;            // element 0..7
    const int pq  = lane & 7;             // step-phase 0..7

    if (is_cons) {
        const float* Whh = gru ? Whh_f : Whh_b;
        const float* bhh = gru ? bhh_f : bhh_b;
        // probe row_ror direction: partner of rotation 2 holds unit (j +- 1)&7
        float nbp = DPP_ROR((float)j, 2);
        const int dstep = (nbp == (float)((j + 1) & 7)) ? 1 : 7;
#pragma unroll
        for (int m = 0; m < 8; ++m) {
            const int k = (j + dstep * m) & 7;
            wr[m] = NL2E * Whh[(j     ) * HDIM + k];
            wz[m] = NL2E * Whh[(j +  8) * HDIM + k];
            wn[m] = L2E2 * Whh[(j + 16) * HDIM + k];
        }
        bhn = L2E2 * bhh[j + 16];
    } else {
        const float* Wih = gru ? Wih_f : Wih_b;
        const float* bih = gru ? bih_f : bih_b;
        const float* bhh = gru ? bhh_f : bhh_b;
        const int IN = gru ? 2 : 4;
        const int pe = blockIdx.x * 8 + pel;
        pxb = gru ? (flow + (size_t)pe * T * 50 + 24)
                  : (bbox + (size_t)pe * T * 4);
#pragma unroll
        for (int jj = 0; jj < 8; ++jj) {
            for (int i = 0; i < 4; ++i) { uir[jj][i] = 0.f; uiz[jj][i] = 0.f; uin[jj][i] = 0.f; }
            for (int i = 0; i < IN; ++i) {
                uir[jj][i] = NL2E * Wih[(jj     ) * IN + i];
                uiz[jj][i] = NL2E * Wih[(jj +  8) * IN + i];
                uin[jj][i] = L2E2 * Wih[(jj + 16) * IN + i];
            }
            cr[jj] = NL2E * (bih[jj]     + bhh[jj]);
            cz[jj] = NL2E * (bih[jj + 8] + bhh[jj + 8]);
            cn[jj] = L2E2 * bih[jj + 16];
        }
    }

    float hj = 0.0f;

    // prologue: produce chunk 0 into buffer 0
    if (!is_cons) {
        float* dst = &projLDS[0][gru][0][0][0];
        if (gru == 0) produce_chunk<4, 4 >(pxb, 0, uir, uiz, uin, cr, cz, cn, dst, pel, pq);
        else          produce_chunk<2, 50>(pxb, 0, uir, uiz, uin, cr, cz, cn, dst, pel, pq);
    }
    __syncthreads();

    for (int c = 0; c < NC; ++c) {
        if (is_cons) {
            hj = consume_chunk(hj, &projLDS[c & 1][gru][0][0][0], eloc, j, wr, wz, wn, bhn);
        } else if (c + 1 < NC) {
            float* dst = &projLDS[(c + 1) & 1][gru][0][0][0];
            if (gru == 0) produce_chunk<4, 4 >(pxb, (c + 1) * CHUNK, uir, uiz, uin, cr, cz, cn, dst, pel, pq);
            else          produce_chunk<2, 50>(pxb, (c + 1) * CHUNK, uir, uiz, uin, cr, cz, cn, dst, pel, pq);
        }
        __syncthreads();
    }

    if (is_cons) sh[gru][eloc][j] = hj;
    __syncthreads();
    if (wave == 0) {
        const int e = blockIdx.x * 8 + eloc;
        out[(size_t)e * HDIM + j] = 0.5f * (sh[0][eloc][j] + sh[1][eloc][j]);
    }
}

extern "C" void kernel_launch(void* const* d_in, const int* in_sizes, int n_in,
                              void* d_out, int out_size, void* d_ws, size_t ws_size,
                              hipStream_t stream) {
    const float* bbox  = (const float*)d_in[0];
    const float* flow  = (const float*)d_in[1];
    const float* Wih_b = (const float*)d_in[2];
    const float* Whh_b = (const float*)d_in[3];
    const float* bih_b = (const float*)d_in[4];
    const float* bhh_b = (const float*)d_in[5];
    const float* Wih_f = (const float*)d_in[6];
    const float* Whh_f = (const float*)d_in[7];
    const float* bih_f = (const float*)d_in[8];
    const float* bhh_f = (const float*)d_in[9];
    float* out = (float*)d_out;

    const int B = out_size / HDIM;            // 1024
    const int T = in_sizes[0] / (4 * B);      // 512

    dim3 grid(B / 8), block(256);
    gru_fused_kernel<<<grid, block, 0, stream>>>(
        bbox, flow, Wih_b, Whh_b, bih_b, bhh_b,
        Wih_f, Whh_f, bih_f, bhh_f, out, T);
}

// Round 6
// 62.463 us; speedup vs baseline: 1.2997x; 1.2997x over previous
//
#include <hip/hip_runtime.h>

#define HDIM 8
#define CHUNK 16   // steps per LDS chunk (T=512 -> 32 chunks)

// ---- fast device math (v_exp_f32 / v_rcp_f32) ----
__device__ __forceinline__ float ex2(float x) {
#if __has_builtin(__builtin_amdgcn_exp2f)
    return __builtin_amdgcn_exp2f(x);
#else
    return exp2f(x);
#endif
}
__device__ __forceinline__ float rcp(float x) {
#if __has_builtin(__builtin_amdgcn_rcpf)
    return __builtin_amdgcn_rcpf(x);
#else
    return 1.0f / x;
#endif
}

// v_mov_b32_dpp row_ror:N (N immediate). 0x120+N = ROW_ROR DPP ctrl.
#define DPP_ROR(v, N)                                                        \
    __int_as_float(__builtin_amdgcn_update_dpp(                              \
        0, __float_as_int(v), 0x120 + (N), 0xF, 0xF, true))

// Lane mapping (same for producer and consumer waves):
//   row = lane>>4 (16-lane DPP row), position p = lane&15
//   element el = (row<<1) | (p&1)   (two elements interleaved per row)
//   hidden unit j = p>>1
// LDS layout: slot [s*64 + lane] (float4) — every wave access is 64
// contiguous 16B slots => conflict-free (2 lanes/bank structural min).

// ---- producer: prescaled input projections for one 16-step chunk ----
// Lane owns (el, j); computes (pr,pz,pn) for its unit over 16 steps and
// writes float4 to its own slot. x loads are 8-lane broadcasts per element.
template <int IN, int STRIDE>
__device__ __forceinline__ void produce_chunk(
    const float* __restrict__ xb, int t0,
    const float (&ur)[4], const float (&uz)[4], const float (&un)[4],
    float cr, float cz, float cn,
    float4* __restrict__ dst, int lane)
{
#pragma unroll
    for (int h = 0; h < 2; ++h) {
        float xs[8][IN];
#pragma unroll
        for (int s = 0; s < 8; ++s) {          // batch loads (issue ahead)
            const float* p = xb + (size_t)(t0 + h * 8 + s) * STRIDE;
            if constexpr (IN == 4) {
                float4 v = *reinterpret_cast<const float4*>(p);
                xs[s][0] = v.x; xs[s][1] = v.y; xs[s][2] = v.z; xs[s][3] = v.w;
            } else {
                float2 v = *reinterpret_cast<const float2*>(p);
                xs[s][0] = v.x; xs[s][1] = v.y;
            }
        }
#pragma unroll
        for (int s = 0; s < 8; ++s) {
            float a = cr, b = cz, c = cn;
#pragma unroll
            for (int i = 0; i < IN; ++i) {
                a = fmaf(ur[i], xs[s][i], a);
                b = fmaf(uz[i], xs[s][i], b);
                c = fmaf(un[i], xs[s][i], c);
            }
            dst[(h * 8 + s) * 64 + lane] = make_float4(a, b, c, 0.0f);
        }
    }
}

// ---- consumer: 16 recurrence steps from LDS projections ----
__device__ __forceinline__ float consume_chunk(
    float hj, const float4* __restrict__ src, int lane,
    const float (&wr)[8], const float (&wz)[8], const float (&wn)[8], float bhn)
{
    float4 pf[4];                       // 3-deep ring prefetch
    pf[0] = src[0 * 64 + lane];
    pf[1] = src[1 * 64 + lane];
    pf[2] = src[2 * 64 + lane];
#pragma unroll
    for (int s = 0; s < CHUNK; ++s) {
        if (s + 3 < CHUNK) pf[(s + 3) & 3] = src[(s + 3) * 64 + lane];
        const float4 P = pf[s & 3];     // (pr, pz, pn, 0) prescaled

        // h all-gather: 7 DPP row-rotations (VALU only)
        const float hx0 = hj;
        const float hx1 = DPP_ROR(hj,  2);
        const float hx2 = DPP_ROR(hj,  4);
        const float hx3 = DPP_ROR(hj,  6);
        const float hx4 = DPP_ROR(hj,  8);
        const float hx5 = DPP_ROR(hj, 10);
        const float hx6 = DPP_ROR(hj, 12);
        const float hx7 = DPP_ROR(hj, 14);

        // balanced trees, proj/bias folded into first pair
        float r01 = fmaf(wr[1], hx1, fmaf(wr[0], hx0, P.x));
        float r23 = fmaf(wr[3], hx3, wr[2] * hx2);
        float r45 = fmaf(wr[5], hx5, wr[4] * hx4);
        float r67 = fmaf(wr[7], hx7, wr[6] * hx6);
        float z01 = fmaf(wz[1], hx1, fmaf(wz[0], hx0, P.y));
        float z23 = fmaf(wz[3], hx3, wz[2] * hx2);
        float z45 = fmaf(wz[5], hx5, wz[4] * hx4);
        float z67 = fmaf(wz[7], hx7, wz[6] * hx6);
        float n01 = fmaf(wn[1], hx1, fmaf(wn[0], hx0, bhn));
        float n23 = fmaf(wn[3], hx3, wn[2] * hx2);
        float n45 = fmaf(wn[5], hx5, wn[4] * hx4);
        float n67 = fmaf(wn[7], hx7, wn[6] * hx6);
        float sr = (r01 + r23) + (r45 + r67);
        float sz = (z01 + z23) + (z45 + z67);
        float sn = (n01 + n23) + (n45 + n67);

        float r = rcp(1.0f + ex2(sr));              // sigmoid (prescaled arg)
        float z = rcp(1.0f + ex2(sz));
        float u = fmaf(r, sn, P.z);                 // 2log2e*(an + r*hn)
        float n = fmaf(-2.0f, rcp(1.0f + ex2(u)), 1.0f);  // tanh
        hj = fmaf(z, hj - n, n);                    // (1-z)*n + z*h
    }
    return hj;
}

// block = 256 threads = 4 waves.
//   wave 0: consumer bbox   wave 1: consumer flow
//   wave 2: producer bbox   wave 3: producer flow
__global__ __launch_bounds__(256, 1)
void gru_fused_kernel(const float* __restrict__ bbox, const float* __restrict__ flow,
                      const float* __restrict__ Wih_b, const float* __restrict__ Whh_b,
                      const float* __restrict__ bih_b, const float* __restrict__ bhh_b,
                      const float* __restrict__ Wih_f, const float* __restrict__ Whh_f,
                      const float* __restrict__ bih_f, const float* __restrict__ bhh_f,
                      float* __restrict__ out, int T)
{
    const float NL2E = -1.4426950408889634f;  // -log2(e)
    const float L2E2 =  2.8853900817779268f;  //  2*log2(e)

    __shared__ float4 projLDS[2][2][CHUNK * 64];    // 64 KiB, lane-linear slots
    __shared__ float sh[2][8][HDIM];

    const int tid  = threadIdx.x;
    const int wave = tid >> 6;
    const int lane = tid & 63;
    const int gru  = wave & 1;            // 0 = bbox, 1 = flow
    const bool is_cons = (wave < 2);
    const int NC = T / CHUNK;             // 32

    const int eloc = ((lane >> 4) << 1) | (lane & 1);   // element 0..7
    const int j    = (lane & 15) >> 1;                  // hidden unit 0..7

    // ---- consumer state ----
    float wr[8], wz[8], wn[8];
    float bhn = 0.0f;
    // ---- producer state ----
    float ur[4] = {0, 0, 0, 0}, uz[4] = {0, 0, 0, 0}, un[4] = {0, 0, 0, 0};
    float cr = 0.0f, cz = 0.0f, cn = 0.0f;
    const float* pxb = nullptr;

    if (is_cons) {
        const float* Whh = gru ? Whh_f : Whh_b;
        const float* bhh = gru ? bhh_f : bhh_b;
        // probe row_ror direction: partner of rotation 2 holds unit (j +- 1)&7
        float nbp = DPP_ROR((float)j, 2);
        const int dstep = (nbp == (float)((j + 1) & 7)) ? 1 : 7;
#pragma unroll
        for (int m = 0; m < 8; ++m) {
            const int k = (j + dstep * m) & 7;
            wr[m] = NL2E * Whh[(j     ) * HDIM + k];
            wz[m] = NL2E * Whh[(j +  8) * HDIM + k];
            wn[m] = L2E2 * Whh[(j + 16) * HDIM + k];
        }
        bhn = L2E2 * bhh[j + 16];
    } else {
        const float* Wih = gru ? Wih_f : Wih_b;
        const float* bih = gru ? bih_f : bih_b;
        const float* bhh = gru ? bhh_f : bhh_b;
        const int IN = gru ? 2 : 4;
        const int pe = blockIdx.x * 8 + eloc;
        pxb = gru ? (flow + (size_t)pe * T * 50 + 24)
                  : (bbox + (size_t)pe * T * 4);
        for (int i = 0; i < IN; ++i) {
            ur[i] = NL2E * Wih[(j     ) * IN + i];
            uz[i] = NL2E * Wih[(j +  8) * IN + i];
            un[i] = L2E2 * Wih[(j + 16) * IN + i];
        }
        cr = NL2E * (bih[j]     + bhh[j]);
        cz = NL2E * (bih[j + 8] + bhh[j + 8]);
        cn = L2E2 * bih[j + 16];
    }

    float hj = 0.0f;

    // prologue: produce chunk 0 into buffer 0
    if (!is_cons) {
        float4* dst = projLDS[0][gru];
        if (gru == 0) produce_chunk<4, 4 >(pxb, 0, ur, uz, un, cr, cz, cn, dst, lane);
        else          produce_chunk<2, 50>(pxb, 0, ur, uz, un, cr, cz, cn, dst, lane);
    }
    __syncthreads();

    for (int c = 0; c < NC; ++c) {
        if (is_cons) {
            hj = consume_chunk(hj, projLDS[c & 1][gru], lane, wr, wz, wn, bhn);
        } else if (c + 1 < NC) {
            float4* dst = projLDS[(c + 1) & 1][gru];
            if (gru == 0) produce_chunk<4, 4 >(pxb, (c + 1) * CHUNK, ur, uz, un, cr, cz, cn, dst, lane);
            else          produce_chunk<2, 50>(pxb, (c + 1) * CHUNK, ur, uz, un, cr, cz, cn, dst, lane);
        }
        __syncthreads();
    }

    if (is_cons) sh[gru][eloc][j] = hj;
    __syncthreads();
    if (wave == 0) {
        const int e = blockIdx.x * 8 + eloc;
        out[(size_t)e * HDIM + j] = 0.5f * (sh[0][eloc][j] + sh[1][eloc][j]);
    }
}

extern "C" void kernel_launch(void* const* d_in, const int* in_sizes, int n_in,
                              void* d_out, int out_size, void* d_ws, size_t ws_size,
                              hipStream_t stream) {
    const float* bbox  = (const float*)d_in[0];
    const float* flow  = (const float*)d_in[1];
    const float* Wih_b = (const float*)d_in[2];
    const float* Whh_b = (const float*)d_in[3];
    const float* bih_b = (const float*)d_in[4];
    const float* bhh_b = (const float*)d_in[5];
    const float* Wih_f = (const float*)d_in[6];
    const float* Whh_f = (const float*)d_in[7];
    const float* bih_f = (const float*)d_in[8];
    const float* bhh_f = (const float*)d_in[9];
    float* out = (float*)d_out;

    const int B = out_size / HDIM;            // 1024
    const int T = in_sizes[0] / (4 * B);      // 512

    dim3 grid(B / 8), block(256);
    gru_fused_kernel<<<grid, block, 0, stream>>>(
        bbox, flow, Wih_b, Whh_b, bih_b, bhh_b,
        Wih_f, Whh_f, bih_f, bhh_f, out, T);
}

// Round 7
// 61.021 us; speedup vs baseline: 1.3304x; 1.0236x over previous
//
#include <hip/hip_runtime.h>

#define HDIM 8
#define CHUNK 16   // steps per LDS chunk (T=512 -> 32 chunks)

typedef float v2f __attribute__((ext_vector_type(2)));

// ---- fast device math (v_exp_f32 / v_rcp_f32) ----
__device__ __forceinline__ float ex2(float x) {
#if __has_builtin(__builtin_amdgcn_exp2f)
    return __builtin_amdgcn_exp2f(x);
#else
    return exp2f(x);
#endif
}
__device__ __forceinline__ float rcp(float x) {
#if __has_builtin(__builtin_amdgcn_rcpf)
    return __builtin_amdgcn_rcpf(x);
#else
    return 1.0f / x;
#endif
}

// v_mov_b32_dpp row_ror:N (N immediate). 0x120+N = ROW_ROR DPP ctrl.
#define DPP_ROR(v, N)                                                        \
    __int_as_float(__builtin_amdgcn_update_dpp(                              \
        0, __float_as_int(v), 0x120 + (N), 0xF, 0xF, true))

// Lane mapping (same for producer and consumer waves):
//   row = lane>>4 (16-lane DPP row), position p = lane&15
//   element el = (row<<1) | (p&1), hidden unit j = p>>1
// LDS layout: slot [s*64 + lane] (float4) — wave accesses are 64 contiguous
// 16B slots => conflict-free.

// ---- producer: prescaled input projections for one 16-step chunk ----
template <int IN, int STRIDE>
__device__ __forceinline__ void produce_chunk(
    const float* __restrict__ xb, int t0,
    const float (&ur)[4], const float (&uz)[4], const float (&un)[4],
    float cr, float cz, float cn,
    float4* __restrict__ dst, int lane)
{
#pragma unroll
    for (int h = 0; h < 2; ++h) {
        float xs[8][IN];
#pragma unroll
        for (int s = 0; s < 8; ++s) {          // batch loads (issue ahead)
            const float* p = xb + (size_t)(t0 + h * 8 + s) * STRIDE;
            if constexpr (IN == 4) {
                float4 v = *reinterpret_cast<const float4*>(p);
                xs[s][0] = v.x; xs[s][1] = v.y; xs[s][2] = v.z; xs[s][3] = v.w;
            } else {
                float2 v = *reinterpret_cast<const float2*>(p);
                xs[s][0] = v.x; xs[s][1] = v.y;
            }
        }
#pragma unroll
        for (int s = 0; s < 8; ++s) {
            float a = cr, b = cz, c = cn;
#pragma unroll
            for (int i = 0; i < IN; ++i) {
                a = fmaf(ur[i], xs[s][i], a);
                b = fmaf(uz[i], xs[s][i], b);
                c = fmaf(un[i], xs[s][i], c);
            }
            dst[(h * 8 + s) * 64 + lane] = make_float4(a, b, c, 0.0f);
        }
    }
}

// ---- consumer: 16 recurrence steps; LDS touched ONLY in the bulk preload ----
__device__ __forceinline__ float consume_chunk(
    float hj, const float4* __restrict__ src, int lane,
    const v2f (&wrz)[8], const float (&wn)[8], float bhn)
{
    // bulk chunk preload into registers: 16 ds_read_b128 back-to-back;
    // whatever lgkmcnt policy the compiler picks costs <= ~1 LDS latency
    // per CHUNK (amortized ~11 cy/step) instead of per step.
    float4 Pb[CHUNK];
#pragma unroll
    for (int s = 0; s < CHUNK; ++s) Pb[s] = src[s * 64 + lane];

#pragma unroll
    for (int s = 0; s < CHUNK; ++s) {
        const float4 P = Pb[s];          // (pr, pz, pn, 0) prescaled

        // h all-gather: 7 DPP row-rotations (VALU only)
        const float hx0 = hj;
        const float hx1 = DPP_ROR(hj,  2);
        const float hx2 = DPP_ROR(hj,  4);
        const float hx3 = DPP_ROR(hj,  6);
        const float hx4 = DPP_ROR(hj,  8);
        const float hx5 = DPP_ROR(hj, 10);
        const float hx6 = DPP_ROR(hj, 12);
        const float hx7 = DPP_ROR(hj, 14);

        // r,z trees packed as float2 (v_pk_fma_f32); two 4-deep halves
        v2f accA = { P.x, P.y };
        accA = __builtin_elementwise_fma((v2f){hx0, hx0}, wrz[0], accA);
        accA = __builtin_elementwise_fma((v2f){hx1, hx1}, wrz[1], accA);
        accA = __builtin_elementwise_fma((v2f){hx2, hx2}, wrz[2], accA);
        accA = __builtin_elementwise_fma((v2f){hx3, hx3}, wrz[3], accA);
        v2f accB = (v2f){hx4, hx4} * wrz[4];
        accB = __builtin_elementwise_fma((v2f){hx5, hx5}, wrz[5], accB);
        accB = __builtin_elementwise_fma((v2f){hx6, hx6}, wrz[6], accB);
        accB = __builtin_elementwise_fma((v2f){hx7, hx7}, wrz[7], accB);
        v2f srz = accA + accB;

        // n tree (scalar, balanced)
        float n01 = fmaf(wn[1], hx1, fmaf(wn[0], hx0, bhn));
        float n23 = fmaf(wn[3], hx3, wn[2] * hx2);
        float n45 = fmaf(wn[5], hx5, wn[4] * hx4);
        float n67 = fmaf(wn[7], hx7, wn[6] * hx6);
        float sn = (n01 + n23) + (n45 + n67);

        float r = rcp(1.0f + ex2(srz.x));            // sigmoid (prescaled arg)
        float z = rcp(1.0f + ex2(srz.y));
        float u = fmaf(r, sn, P.z);                  // 2log2e*(an + r*hn)
        float n = fmaf(-2.0f, rcp(1.0f + ex2(u)), 1.0f);   // tanh
        hj = fmaf(z, hj - n, n);                     // (1-z)*n + z*h
    }
    return hj;
}

// block = 256 threads = 4 waves.
//   wave 0: consumer bbox   wave 1: consumer flow
//   wave 2: producer bbox   wave 3: producer flow
__global__ __launch_bounds__(256, 1)
void gru_fused_kernel(const float* __restrict__ bbox, const float* __restrict__ flow,
                      const float* __restrict__ Wih_b, const float* __restrict__ Whh_b,
                      const float* __restrict__ bih_b, const float* __restrict__ bhh_b,
                      const float* __restrict__ Wih_f, const float* __restrict__ Whh_f,
                      const float* __restrict__ bih_f, const float* __restrict__ bhh_f,
                      float* __restrict__ out, int T)
{
    const float NL2E = -1.4426950408889634f;  // -log2(e)
    const float L2E2 =  2.8853900817779268f;  //  2*log2(e)

    __shared__ float4 projLDS[2][2][CHUNK * 64];    // 64 KiB, lane-linear slots
    __shared__ float sh[2][8][HDIM];

    const int tid  = threadIdx.x;
    const int wave = tid >> 6;
    const int lane = tid & 63;
    const int gru  = wave & 1;            // 0 = bbox, 1 = flow
    const bool is_cons = (wave < 2);
    const int NC = T / CHUNK;             // 32

    const int eloc = ((lane >> 4) << 1) | (lane & 1);   // element 0..7
    const int j    = (lane & 15) >> 1;                  // hidden unit 0..7

    // ---- consumer state ----
    v2f wrz[8];
    float wn[8];
    float bhn = 0.0f;
    // ---- producer state ----
    float ur[4] = {0, 0, 0, 0}, uz[4] = {0, 0, 0, 0}, un[4] = {0, 0, 0, 0};
    float cr = 0.0f, cz = 0.0f, cn = 0.0f;
    const float* pxb = nullptr;

    if (is_cons) {
        const float* Whh = gru ? Whh_f : Whh_b;
        const float* bhh = gru ? bhh_f : bhh_b;
        // probe row_ror direction: partner of rotation 2 holds unit (j +- 1)&7
        float nbp = DPP_ROR((float)j, 2);
        const int dstep = (nbp == (float)((j + 1) & 7)) ? 1 : 7;
#pragma unroll
        for (int m = 0; m < 8; ++m) {
            const int k = (j + dstep * m) & 7;
            wrz[m] = (v2f){ NL2E * Whh[(j    ) * HDIM + k],
                            NL2E * Whh[(j + 8) * HDIM + k] };
            wn[m]  = L2E2 * Whh[(j + 16) * HDIM + k];
        }
        bhn = L2E2 * bhh[j + 16];
    } else {
        const float* Wih = gru ? Wih_f : Wih_b;
        const float* bih = gru ? bih_f : bih_b;
        const float* bhh = gru ? bhh_f : bhh_b;
        const int IN = gru ? 2 : 4;
        const int pe = blockIdx.x * 8 + eloc;
        pxb = gru ? (flow + (size_t)pe * T * 50 + 24)
                  : (bbox + (size_t)pe * T * 4);
        for (int i = 0; i < IN; ++i) {
            ur[i] = NL2E * Wih[(j     ) * IN + i];
            uz[i] = NL2E * Wih[(j +  8) * IN + i];
            un[i] = L2E2 * Wih[(j + 16) * IN + i];
        }
        cr = NL2E * (bih[j]     + bhh[j]);
        cz = NL2E * (bih[j + 8] + bhh[j + 8]);
        cn = L2E2 * bih[j + 16];
    }

    float hj = 0.0f;

    // prologue: produce chunk 0 into buffer 0
    if (!is_cons) {
        float4* dst = projLDS[0][gru];
        if (gru == 0) produce_chunk<4, 4 >(pxb, 0, ur, uz, un, cr, cz, cn, dst, lane);
        else          produce_chunk<2, 50>(pxb, 0, ur, uz, un, cr, cz, cn, dst, lane);
    }
    __syncthreads();

    for (int c = 0; c < NC; ++c) {
        if (is_cons) {
            hj = consume_chunk(hj, projLDS[c & 1][gru], lane, wrz, wn, bhn);
        } else if (c + 1 < NC) {
            float4* dst = projLDS[(c + 1) & 1][gru];
            if (gru == 0) produce_chunk<4, 4 >(pxb, (c + 1) * CHUNK, ur, uz, un, cr, cz, cn, dst, lane);
            else          produce_chunk<2, 50>(pxb, (c + 1) * CHUNK, ur, uz, un, cr, cz, cn, dst, lane);
        }
        __syncthreads();
    }

    if (is_cons) sh[gru][eloc][j] = hj;
    __syncthreads();
    if (wave == 0) {
        const int e = blockIdx.x * 8 + eloc;
        out[(size_t)e * HDIM + j] = 0.5f * (sh[0][eloc][j] + sh[1][eloc][j]);
    }
}

extern "C" void kernel_launch(void* const* d_in, const int* in_sizes, int n_in,
                              void* d_out, int out_size, void* d_ws, size_t ws_size,
                              hipStream_t stream) {
    const float* bbox  = (const float*)d_in[0];
    const float* flow  = (const float*)d_in[1];
    const float* Wih_b = (const float*)d_in[2];
    const float* Whh_b = (const float*)d_in[3];
    const float* bih_b = (const float*)d_in[4];
    const float* bhh_b = (const float*)d_in[5];
    const float* Wih_f = (const float*)d_in[6];
    const float* Whh_f = (const float*)d_in[7];
    const float* bih_f = (const float*)d_in[8];
    const float* bhh_f = (const float*)d_in[9];
    float* out = (float*)d_out;

    const int B = out_size / HDIM;            // 1024
    const int T = in_sizes[0] / (4 * B);      // 512

    dim3 grid(B / 8), block(256);
    gru_fused_kernel<<<grid, block, 0, stream>>>(
        bbox, flow, Wih_b, Whh_b, bih_b, bhh_b,
        Wih_f, Whh_f, bih_f, bhh_f, out, T);
}

// Round 8
// 55.972 us; speedup vs baseline: 1.4504x; 1.0902x over previous
//
#include <hip/hip_runtime.h>

#define HDIM 8
#define CHUNK 16   // steps per LDS chunk (T=512 -> 32 chunks)

typedef float v4f __attribute__((ext_vector_type(4)));
typedef float v2f __attribute__((ext_vector_type(2)));

// ---- fast device math (v_exp_f32 / v_rcp_f32) ----
__device__ __forceinline__ float ex2(float x) {
#if __has_builtin(__builtin_amdgcn_exp2f)
    return __builtin_amdgcn_exp2f(x);
#else
    return exp2f(x);
#endif
}
__device__ __forceinline__ float rcp(float x) {
#if __has_builtin(__builtin_amdgcn_rcpf)
    return __builtin_amdgcn_rcpf(x);
#else
    return 1.0f / x;
#endif
}

// v_mov_b32_dpp row_ror:N (N immediate). 0x120+N = ROW_ROR DPP ctrl.
#define DPP_ROR(v, N)                                                        \
    __int_as_float(__builtin_amdgcn_update_dpp(                              \
        0, __float_as_int(v), 0x120 + (N), 0xF, 0xF, true))

// Lane mapping (producer and consumer identical):
//   row = lane>>4 (16-lane DPP row), p = lane&15
//   element el = (row<<1)|(p&1), hidden unit j = p>>1
// LDS layout: slot [s*64 + lane] (float4) — wave accesses are 64 contiguous
// 16B slots => conflict-free.

// Keep-alive: forces all 16 named vector values to be materialized in VGPRs
// at this program point (=> the loads feeding them are complete; one combined
// compiler-inserted waitcnt instead of 16 per-use waits).
#define KEEPALIVE16(a)                                                       \
    asm volatile("" : "+v"(a##0), "+v"(a##1), "+v"(a##2), "+v"(a##3),        \
                      "+v"(a##4), "+v"(a##5), "+v"(a##6), "+v"(a##7),        \
                      "+v"(a##8), "+v"(a##9), "+v"(a##10), "+v"(a##11),      \
                      "+v"(a##12), "+v"(a##13), "+v"(a##14), "+v"(a##15))

// ---- producer: prescaled input projections for one 16-step chunk ----
// All 16 x-loads issued up-front and pinned via keep-alive (one HBM latency
// per chunk), then 16 projection computes + conflict-free LDS writes.
template <int IN, int STRIDE>
__device__ __forceinline__ void produce_chunk(
    const float* __restrict__ xb, int t0,
    const float (&ur)[4], const float (&uz)[4], const float (&un)[4],
    float cr, float cz, float cn,
    float4* __restrict__ dst, int lane)
{
    const float* bp = xb + (size_t)t0 * STRIDE;
#define PLOAD4(i) v4f x##i = *reinterpret_cast<const v4f*>(bp + (i) * STRIDE);
#define PLOAD2(i) v2f x##i = *reinterpret_cast<const v2f*>(bp + (i) * STRIDE);
#define PSTORE(i)                                                            \
    {                                                                        \
        float a = cr, b = cz, c = cn;                                        \
        _Pragma("unroll")                                                    \
        for (int i2 = 0; i2 < IN; ++i2) {                                    \
            a = fmaf(ur[i2], x##i[i2], a);                                   \
            b = fmaf(uz[i2], x##i[i2], b);                                   \
            c = fmaf(un[i2], x##i[i2], c);                                   \
        }                                                                    \
        dst[(i) * 64 + lane] = make_float4(a, b, c, 0.0f);                   \
    }
    if constexpr (IN == 4) {
        PLOAD4(0) PLOAD4(1) PLOAD4(2) PLOAD4(3) PLOAD4(4) PLOAD4(5)
        PLOAD4(6) PLOAD4(7) PLOAD4(8) PLOAD4(9) PLOAD4(10) PLOAD4(11)
        PLOAD4(12) PLOAD4(13) PLOAD4(14) PLOAD4(15)
        KEEPALIVE16(x);
        PSTORE(0) PSTORE(1) PSTORE(2) PSTORE(3) PSTORE(4) PSTORE(5)
        PSTORE(6) PSTORE(7) PSTORE(8) PSTORE(9) PSTORE(10) PSTORE(11)
        PSTORE(12) PSTORE(13) PSTORE(14) PSTORE(15)
    } else {
        PLOAD2(0) PLOAD2(1) PLOAD2(2) PLOAD2(3) PLOAD2(4) PLOAD2(5)
        PLOAD2(6) PLOAD2(7) PLOAD2(8) PLOAD2(9) PLOAD2(10) PLOAD2(11)
        PLOAD2(12) PLOAD2(13) PLOAD2(14) PLOAD2(15)
        KEEPALIVE16(x);
        PSTORE(0) PSTORE(1) PSTORE(2) PSTORE(3) PSTORE(4) PSTORE(5)
        PSTORE(6) PSTORE(7) PSTORE(8) PSTORE(9) PSTORE(10) PSTORE(11)
        PSTORE(12) PSTORE(13) PSTORE(14) PSTORE(15)
    }
#undef PLOAD4
#undef PLOAD2
#undef PSTORE
}

// ---- consumer: 16 recurrence steps; LDS read ONLY in the pinned preload ----
__device__ __forceinline__ float consume_chunk(
    float hj, const float4* __restrict__ src, int lane,
    const float (&wr)[8], const float (&wz)[8], const float (&wn)[8], float bhn)
{
    const v4f* sp = reinterpret_cast<const v4f*>(src);
#define CLOAD(i) v4f p##i = sp[(i) * 64 + lane];
    CLOAD(0) CLOAD(1) CLOAD(2) CLOAD(3) CLOAD(4) CLOAD(5) CLOAD(6) CLOAD(7)
    CLOAD(8) CLOAD(9) CLOAD(10) CLOAD(11) CLOAD(12) CLOAD(13) CLOAD(14) CLOAD(15)
    KEEPALIVE16(p);   // 16 ds_read_b128 complete here; 64 VGPRs live; no LDS below
#undef CLOAD

#define STEP(P)                                                              \
    {                                                                        \
        const float hx0 = hj;                                                \
        const float hx1 = DPP_ROR(hj, 2);                                    \
        const float hx2 = DPP_ROR(hj, 4);                                    \
        const float hx3 = DPP_ROR(hj, 6);                                    \
        const float hx4 = DPP_ROR(hj, 8);                                    \
        const float hx5 = DPP_ROR(hj, 10);                                   \
        const float hx6 = DPP_ROR(hj, 12);                                   \
        const float hx7 = DPP_ROR(hj, 14);                                   \
        float r01 = fmaf(wr[1], hx1, fmaf(wr[0], hx0, P.x));                 \
        float r23 = fmaf(wr[3], hx3, wr[2] * hx2);                           \
        float r45 = fmaf(wr[5], hx5, wr[4] * hx4);                           \
        float r67 = fmaf(wr[7], hx7, wr[6] * hx6);                           \
        float z01 = fmaf(wz[1], hx1, fmaf(wz[0], hx0, P.y));                 \
        float z23 = fmaf(wz[3], hx3, wz[2] * hx2);                           \
        float z45 = fmaf(wz[5], hx5, wz[4] * hx4);                           \
        float z67 = fmaf(wz[7], hx7, wz[6] * hx6);                           \
        float n01 = fmaf(wn[1], hx1, fmaf(wn[0], hx0, bhn));                 \
        float n23 = fmaf(wn[3], hx3, wn[2] * hx2);                           \
        float n45 = fmaf(wn[5], hx5, wn[4] * hx4);                           \
        float n67 = fmaf(wn[7], hx7, wn[6] * hx6);                           \
        float sr = (r01 + r23) + (r45 + r67);                                \
        float sz = (z01 + z23) + (z45 + z67);                                \
        float sn = (n01 + n23) + (n45 + n67);                                \
        float r = rcp(1.0f + ex2(sr));                                       \
        float z = rcp(1.0f + ex2(sz));                                       \
        float u = fmaf(r, sn, P.z);                                          \
        float n = fmaf(-2.0f, rcp(1.0f + ex2(u)), 1.0f);                     \
        hj = fmaf(z, hj - n, n);                                             \
    }
    STEP(p0) STEP(p1) STEP(p2) STEP(p3) STEP(p4) STEP(p5) STEP(p6) STEP(p7)
    STEP(p8) STEP(p9) STEP(p10) STEP(p11) STEP(p12) STEP(p13) STEP(p14) STEP(p15)
#undef STEP
    return hj;
}

// block = 256 threads = 4 waves.
//   wave 0: consumer bbox   wave 1: consumer flow
//   wave 2: producer bbox   wave 3: producer flow
__global__ __launch_bounds__(256, 1)
void gru_fused_kernel(const float* __restrict__ bbox, const float* __restrict__ flow,
                      const float* __restrict__ Wih_b, const float* __restrict__ Whh_b,
                      const float* __restrict__ bih_b, const float* __restrict__ bhh_b,
                      const float* __restrict__ Wih_f, const float* __restrict__ Whh_f,
                      const float* __restrict__ bih_f, const float* __restrict__ bhh_f,
                      float* __restrict__ out, int T)
{
    const float NL2E = -1.4426950408889634f;  // -log2(e)
    const float L2E2 =  2.8853900817779268f;  //  2*log2(e)

    __shared__ float4 projLDS[2][2][CHUNK * 64];    // 64 KiB, lane-linear slots
    __shared__ float sh[2][8][HDIM];

    const int tid  = threadIdx.x;
    const int wave = tid >> 6;
    const int lane = tid & 63;
    const int gru  = wave & 1;            // 0 = bbox, 1 = flow
    const bool is_cons = (wave < 2);
    const int NC = T / CHUNK;             // 32

    const int eloc = ((lane >> 4) << 1) | (lane & 1);   // element 0..7
    const int j    = (lane & 15) >> 1;                  // hidden unit 0..7

    // ---- consumer state ----
    float wr[8], wz[8], wn[8];
    float bhn = 0.0f;
    // ---- producer state ----
    float ur[4] = {0, 0, 0, 0}, uz[4] = {0, 0, 0, 0}, un[4] = {0, 0, 0, 0};
    float cr = 0.0f, cz = 0.0f, cn = 0.0f;
    const float* pxb = nullptr;

    if (is_cons) {
        const float* Whh = gru ? Whh_f : Whh_b;
        const float* bhh = gru ? bhh_f : bhh_b;
        // probe row_ror direction: partner of rotation 2 holds unit (j +- 1)&7
        float nbp = DPP_ROR((float)j, 2);
        const int dstep = (nbp == (float)((j + 1) & 7)) ? 1 : 7;
#pragma unroll
        for (int m = 0; m < 8; ++m) {
            const int k = (j + dstep * m) & 7;
            wr[m] = NL2E * Whh[(j     ) * HDIM + k];
            wz[m] = NL2E * Whh[(j +  8) * HDIM + k];
            wn[m] = L2E2 * Whh[(j + 16) * HDIM + k];
        }
        bhn = L2E2 * bhh[j + 16];
    } else {
        const float* Wih = gru ? Wih_f : Wih_b;
        const float* bih = gru ? bih_f : bih_b;
        const float* bhh = gru ? bhh_f : bhh_b;
        const int IN = gru ? 2 : 4;
        const int pe = blockIdx.x * 8 + eloc;
        pxb = gru ? (flow + (size_t)pe * T * 50 + 24)
                  : (bbox + (size_t)pe * T * 4);
        for (int i = 0; i < IN; ++i) {
            ur[i] = NL2E * Wih[(j     ) * IN + i];
            uz[i] = NL2E * Wih[(j +  8) * IN + i];
            un[i] = L2E2 * Wih[(j + 16) * IN + i];
        }
        cr = NL2E * (bih[j]     + bhh[j]);
        cz = NL2E * (bih[j + 8] + bhh[j + 8]);
        cn = L2E2 * bih[j + 16];
    }

    float hj = 0.0f;

    // prologue: produce chunk 0 into buffer 0
    if (!is_cons) {
        float4* dst = projLDS[0][gru];
        if (gru == 0) produce_chunk<4, 4 >(pxb, 0, ur, uz, un, cr, cz, cn, dst, lane);
        else          produce_chunk<2, 50>(pxb, 0, ur, uz, un, cr, cz, cn, dst, lane);
    }
    __syncthreads();

    for (int c = 0; c < NC; ++c) {
        if (is_cons) {
            hj = consume_chunk(hj, projLDS[c & 1][gru], lane, wr, wz, wn, bhn);
        } else if (c + 1 < NC) {
            float4* dst = projLDS[(c + 1) & 1][gru];
            if (gru == 0) produce_chunk<4, 4 >(pxb, (c + 1) * CHUNK, ur, uz, un, cr, cz, cn, dst, lane);
            else          produce_chunk<2, 50>(pxb, (c + 1) * CHUNK, ur, uz, un, cr, cz, cn, dst, lane);
        }
        __syncthreads();
    }

    if (is_cons) sh[gru][eloc][j] = hj;
    __syncthreads();
    if (wave == 0) {
        const int e = blockIdx.x * 8 + eloc;
        out[(size_t)e * HDIM + j] = 0.5f * (sh[0][eloc][j] + sh[1][eloc][j]);
    }
}

extern "C" void kernel_launch(void* const* d_in, const int* in_sizes, int n_in,
                              void* d_out, int out_size, void* d_ws, size_t ws_size,
                              hipStream_t stream) {
    const float* bbox  = (const float*)d_in[0];
    const float* flow  = (const float*)d_in[1];
    const float* Wih_b = (const float*)d_in[2];
    const float* Whh_b = (const float*)d_in[3];
    const float* bih_b = (const float*)d_in[4];
    const float* bhh_b = (const float*)d_in[5];
    const float* Wih_f = (const float*)d_in[6];
    const float* Whh_f = (const float*)d_in[7];
    const float* bih_f = (const float*)d_in[8];
    const float* bhh_f = (const float*)d_in[9];
    float* out = (float*)d_out;

    const int B = out_size / HDIM;            // 1024
    const int T = in_sizes[0] / (4 * B);      // 512

    dim3 grid(B / 8), block(256);
    gru_fused_kernel<<<grid, block, 0, stream>>>(
        bbox, flow, Wih_b, Whh_b, bih_b, bhh_b,
        Wih_f, Whh_f, bih_f, bhh_f, out, T);
}